// Round 10
// baseline (574.312 us; speedup 1.0000x reference)
//
#include <hip/hip_runtime.h>
#include <cstdint>

typedef __attribute__((ext_vector_type(8))) short short8;
typedef __attribute__((ext_vector_type(4))) float f32x4;
typedef __attribute__((ext_vector_type(4))) unsigned short us4;
typedef unsigned short u16;

static __device__ __forceinline__ u16 f2bf(float f) {
  union { float f; unsigned u; } x; x.f = f;
  return (u16)((x.u + 0x7FFFu + ((x.u >> 16) & 1u)) >> 16);
}

static __device__ __forceinline__ float wred_max(float v) {
#pragma unroll
  for (int o = 32; o > 0; o >>= 1) v = fmaxf(v, __shfl_xor(v, o, 64));
  return v;
}
static __device__ __forceinline__ float wred_sum(float v) {
#pragma unroll
  for (int o = 32; o > 0; o >>= 1) v += __shfl_xor(v, o, 64);
  return v;
}

static __device__ __forceinline__ void gload16(const void* g, void* l) {
  __builtin_amdgcn_global_load_lds(
      (const __attribute__((address_space(1))) unsigned int*)g,
      (__attribute__((address_space(3))) unsigned int*)l, 16, 0, 0);
}

// ---------------------------------------------------------------------------
// bf16 MFMA GEMM body. A[M][K] bf16, Bt[N][K] bf16.
// cm=1: Vtb transpose-split epilogue (row rw = n*2+b composite).
// ---------------------------------------------------------------------------
struct GemmP {
  const u16* A; const u16* B; void* C; const float* bias;
  int K, lda, ldb, crs, ccs;
  int azi, bzi, czi, biasdz;
  long aso, asi, bso, bsi, cso, csi, biassz;
  float scale; int relu; int cbf16; int cm;
};

template<int ROWS>
static __device__ __forceinline__ void stage_t(const u16* g, int ld, u16* lds,
                                               int w, int lane) {
#pragma unroll
  for (int j = 0; j < ROWS / 32; ++j) {
    const int idx = w * (ROWS / 32) + j;
    const int r = idx * 8 + (lane >> 3);
    const int gc = ((lane & 7) ^ (r & 7)) * 8;  // swizzled 16B granule
    gload16(g + (long)r * ld + gc, lds + idx * 512);
  }
}

template<int BM, int BN>
static __device__ void gbody(const GemmP& p, int tm, int tn, int z, u16* Al, u16* Bl) {
  constexpr int WTM = BM / 2, WTN = BN / 2;
  constexpr int FM = WTM / 16, FN = WTN / 16;
  const int tid = threadIdx.x, lane = tid & 63, w = tid >> 6;
  const int wr = w >> 1, wc = w & 1, lr = lane & 15, lk4 = lane >> 4;
  const long ab = (long)(z / p.azi) * p.aso + (long)(z % p.azi) * p.asi + (long)tm * p.lda;
  const long bb = (long)(z / p.bzi) * p.bso + (long)(z % p.bzi) * p.bsi + (long)tn * p.ldb;
  const long cb = (long)(z / p.czi) * p.cso + (long)(z % p.czi) * p.csi;
  const long boff = p.biasdz ? (long)(z / p.biasdz) * p.biassz : 0;

  f32x4 acc[FM][FN];
#pragma unroll
  for (int i = 0; i < FM; ++i)
#pragma unroll
    for (int j = 0; j < FN; ++j) acc[i][j] = (f32x4)(0.0f);

  const u16* Ag = p.A + ab;
  const u16* Bg = p.B + bb;
  stage_t<BM>(Ag, p.lda, Al, w, lane);
  stage_t<BN>(Bg, p.ldb, Bl, w, lane);
  __syncthreads();

  const int nt = p.K >> 6;
  for (int t = 0; t < nt; ++t) {
    const int cur = t & 1;
    if (t + 1 < nt) {
      stage_t<BM>(Ag + (long)(t + 1) * 64, p.lda, Al + (cur ^ 1) * BM * 64, w, lane);
      stage_t<BN>(Bg + (long)(t + 1) * 64, p.ldb, Bl + (cur ^ 1) * BN * 64, w, lane);
    }
    short8 af[FM][2], bfv[FN][2];
#pragma unroll
    for (int ks = 0; ks < 2; ++ks) {
#pragma unroll
      for (int mi = 0; mi < FM; ++mi) {
        const int row = wr * WTM + mi * 16 + lr;
        const int off = row * 128 + ((ks * 4 + lk4) ^ (row & 7)) * 16;
        af[mi][ks] = *(const short8*)((const char*)(Al + cur * BM * 64) + off);
      }
#pragma unroll
      for (int ni = 0; ni < FN; ++ni) {
        const int row = wc * WTN + ni * 16 + lr;
        const int off = row * 128 + ((ks * 4 + lk4) ^ (row & 7)) * 16;
        bfv[ni][ks] = *(const short8*)((const char*)(Bl + cur * BN * 64) + off);
      }
    }
#pragma unroll
    for (int ks = 0; ks < 2; ++ks)
#pragma unroll
      for (int mi = 0; mi < FM; ++mi)
#pragma unroll
        for (int ni = 0; ni < FN; ++ni)
          acc[mi][ni] = __builtin_amdgcn_mfma_f32_16x16x32_bf16(af[mi][ks], bfv[ni][ks],
                                                                acc[mi][ni], 0, 0, 0);
    __syncthreads();
  }

  const int kg = lk4 * 4;
#pragma unroll
  for (int ni = 0; ni < FN; ++ni) {
    const int col = tn + wc * WTN + ni * 16 + lr;
    const float bv = p.bias ? p.bias[boff + col] : 0.0f;
#pragma unroll
    for (int mi = 0; mi < FM; ++mi) {
      const int rb = tm + wr * WTM + mi * 16 + kg;
#pragma unroll
      for (int r = 0; r < 4; ++r) {
        const int rw = rb + r;
        float v = acc[mi][ni][r] * p.scale + bv;
        if (p.relu) v = fmaxf(v, 0.0f);
        if (p.cm) {
          const long ci = (long)(rw & 1) * 524288 + (long)col * 1024 + (rw >> 1);
          ((u16*)p.C)[ci] = f2bf(v);
        } else {
          const long ci = cb + (long)rw * p.crs + (long)col * p.ccs;
          if (p.cbf16) ((u16*)p.C)[ci] = f2bf(v);
          else ((float*)p.C)[ci] = v;
        }
      }
    }
  }
}

template<int BM, int BN>
__global__ __launch_bounds__(256, 4) void gemm_k(GemmP p) {
  __shared__ __align__(16) u16 Al[2 * BM * 64];
  __shared__ __align__(16) u16 Bl[2 * BN * 64];
  gbody<BM, BN>(p, blockIdx.y * BM, blockIdx.x * BN, blockIdx.z, Al, Bl);
}

// grouped qk-proj (512 tiles of 64x64) + v-proj (256 tiles of 64x64, cm epilogue)
__global__ __launch_bounds__(256, 4) void qkv2_k(GemmP q, GemmP v) {
  __shared__ __align__(16) u16 Al[2 * 64 * 64];
  __shared__ __align__(16) u16 Bl[2 * 64 * 64];
  const int id = blockIdx.x;
  if (id < 512) gbody<64, 64>(q, (id / 16) * 64, (id % 16) * 64, 0, Al, Bl);
  else { const int u = id - 512; gbody<64, 64>(v, (u / 8) * 64, (u % 8) * 64, 0, Al, Bl); }
}

// ALL-layer conv k/v projections: 128x128 tiles. z = l*4 + g*2 + b
__global__ __launch_bounds__(256, 2) void convkv_k(const u16* mempb, const u16* convwb,
                                                   const float* convb, float* kvall) {
  __shared__ __align__(16) u16 Al[2 * 128 * 64];
  __shared__ __align__(16) u16 Bl[2 * 128 * 64];
  const int id = blockIdx.x;
  const int z = id >> 6, rr = id & 63;
  const int l = z >> 2, g = (z >> 1) & 1, b = z & 1;
  GemmP p{};
  p.A = mempb + g * 2097152 + b * 512; p.lda = 1024;
  p.B = convwb + ((long)(l * 3 + 1 + g)) * 262144; p.ldb = 512;
  p.C = kvall + (long)z * 1048576; p.crs = 1; p.ccs = 2048;
  p.bias = convb + (l * 3 + 1 + g) * 512;
  p.K = 512; p.azi = p.bzi = p.czi = 1; p.scale = 1.0f;
  gbody<128, 128>(p, (rr >> 2) * 128, (rr & 3) * 128, 0, Al, Bl);
}

// ---------------------------------------------------------------------------
// Fused flash attention
// ---------------------------------------------------------------------------
__global__ __launch_bounds__(256) void flash_attn(const u16* qkb, const u16* Vtb, u16* aob) {
  const int zh = blockIdx.x, b = zh >> 3, h = zh & 7;
  const int qt = blockIdx.y;
  const int tid = threadIdx.x, lane = tid & 63, w = tid >> 6;
  const int lr = lane & 15, g = lane >> 4;

  __shared__ __align__(16) u16 Kl[2][64 * 64];
  __shared__ __align__(16) u16 Vl[2][64 * 64];
  __shared__ __align__(16) u16 Pl[4][16 * 64];

  const int nrow = qt * 64 + w * 16 + lr;
  const long qbase = ((long)(nrow * 2 + b)) * 1024 + h * 64;
  const short8 q0 = *(const short8*)&qkb[qbase + g * 8];
  const short8 q1 = *(const short8*)&qkb[qbase + 32 + g * 8];

  f32x4 acc_o[4];
#pragma unroll
  for (int i = 0; i < 4; ++i) acc_o[i] = (f32x4)(0.0f);
  float m_run = -3e38f, l_run = 0.0f;

  auto stg = [&](int buf, int t) {
    const int m0 = t * 64;
#pragma unroll
    for (int j = 0; j < 2; ++j) {
      const int c = w * 2 + j;
      const int row = c * 8 + (lane >> 3);
      const int src = (lane & 7) ^ (row & 7);
      gload16(qkb + ((long)((m0 + row) * 2 + b)) * 1024 + 512 + h * 64 + src * 8,
              &Kl[buf][c * 512]);
      gload16(Vtb + (long)b * 524288 + ((long)(h * 64 + row)) * 1024 + m0 + src * 8,
              &Vl[buf][c * 512]);
    }
  };

  stg(0, 0);
  __syncthreads();

  for (int t = 0; t < 16; ++t) {
    const int cur = t & 1;
    if (t < 15) stg(cur ^ 1, t + 1);

    f32x4 s_acc[4];
#pragma unroll
    for (int ks = 0; ks < 4; ++ks) {
      const int krow = ks * 16 + lr;
      const short8 k0 = *(const short8*)&Kl[cur][krow * 64 + ((g ^ (krow & 7)) * 8)];
      const short8 k1 = *(const short8*)&Kl[cur][krow * 64 + (((4 + g) ^ (krow & 7)) * 8)];
      f32x4 z4 = (f32x4)(0.0f);
      z4 = __builtin_amdgcn_mfma_f32_16x16x32_bf16(k0, q0, z4, 0, 0, 0);
      z4 = __builtin_amdgcn_mfma_f32_16x16x32_bf16(k1, q1, z4, 0, 0, 0);
      s_acc[ks] = z4;
    }

    float mx = -3e38f;
#pragma unroll
    for (int ks = 0; ks < 4; ++ks)
#pragma unroll
      for (int r = 0; r < 4; ++r) mx = fmaxf(mx, s_acc[ks][r]);
    mx = fmaxf(mx, __shfl_xor(mx, 16, 64));
    mx = fmaxf(mx, __shfl_xor(mx, 32, 64));
    mx *= 0.125f;
    const float m_new = fmaxf(m_run, mx);
    const float alpha = __expf(m_run - m_new);
    float psum = 0.0f;
    u16 pb[4][4];
#pragma unroll
    for (int ks = 0; ks < 4; ++ks)
#pragma unroll
      for (int r = 0; r < 4; ++r) {
        const float pv = __expf(s_acc[ks][r] * 0.125f - m_new);
        psum += pv;
        pb[ks][r] = f2bf(pv);
      }
    psum += __shfl_xor(psum, 16, 64);
    psum += __shfl_xor(psum, 32, 64);
    l_run = l_run * alpha + psum;
    m_run = m_new;
#pragma unroll
    for (int i = 0; i < 4; ++i) acc_o[i] *= alpha;

#pragma unroll
    for (int ks = 0; ks < 4; ++ks)
#pragma unroll
      for (int r = 0; r < 4; ++r) {
        const int m = ks * 16 + g * 4 + r;
        Pl[w][lr * 64 + (((m >> 3) ^ (lr & 7)) * 8) + (m & 7)] = pb[ks][r];
      }

#pragma unroll
    for (int mh = 0; mh < 2; ++mh) {
      const short8 pt = *(const short8*)&Pl[w][lr * 64 + (((mh * 4 + g) ^ (lr & 7)) * 8)];
#pragma unroll
      for (int ds = 0; ds < 4; ++ds) {
        const int drow = ds * 16 + lr;
        const short8 vt = *(const short8*)&Vl[cur][drow * 64 + (((mh * 4 + g) ^ (drow & 7)) * 8)];
        acc_o[ds] = __builtin_amdgcn_mfma_f32_16x16x32_bf16(vt, pt, acc_o[ds], 0, 0, 0);
      }
    }
    __syncthreads();
  }

  const float invl = 1.0f / l_run;
#pragma unroll
  for (int ds = 0; ds < 4; ++ds)
#pragma unroll
    for (int r = 0; r < 4; ++r) {
      const int d = ds * 16 + g * 4 + r;
      aob[((long)(nrow * 2 + b)) * 512 + h * 64 + d] = f2bf(acc_o[ds][r] * invl);
    }
}

// ---------------------------------------------------------------------------
// LayerNorm D=512; resmode 0/1/2; optional bf16 out; optional bf16(out+add2)
// ---------------------------------------------------------------------------
__global__ __launch_bounds__(256) void ln512(const float* a, const float* res, int resmode,
                                             const float* g, const float* bt,
                                             float* out, u16* obf,
                                             const float* add2, u16* obf2) {
  const int row = blockIdx.x * 4 + (threadIdx.x >> 6);
  const int lane = threadIdx.x & 63;
  const float* ar = a + (long)row * 512;
  f32x4 x[2];
#pragma unroll
  for (int i = 0; i < 2; ++i) {
    const int idx = (i * 64 + lane) * 4;
    x[i] = *(const f32x4*)&ar[idx];
    if (resmode == 1) x[i] += *(const f32x4*)&res[(long)row * 512 + idx];
    else if (resmode == 2) x[i] += *(const f32x4*)&res[(row & 1) * 512 + idx];
  }
  float s = 0.f;
#pragma unroll
  for (int i = 0; i < 2; ++i)
#pragma unroll
    for (int j = 0; j < 4; ++j) s += x[i][j];
  const float mean = wred_sum(s) * (1.0f / 512.0f);
  float vv = 0.f;
#pragma unroll
  for (int i = 0; i < 2; ++i)
#pragma unroll
    for (int j = 0; j < 4; ++j) { const float d = x[i][j] - mean; vv += d * d; }
  vv = wred_sum(vv) * (1.0f / 512.0f);
  const float rs = rsqrtf(vv + 1e-5f);
#pragma unroll
  for (int i = 0; i < 2; ++i) {
    const int idx = (i * 64 + lane) * 4;
    const f32x4 gv = *(const f32x4*)&g[idx];
    const f32x4 bv = *(const f32x4*)&bt[idx];
    f32x4 o;
#pragma unroll
    for (int j = 0; j < 4; ++j) o[j] = (x[i][j] - mean) * rs * gv[j] + bv[j];
    *(f32x4*)&out[(long)row * 512 + idx] = o;
    if (obf) {
      us4 ov;
#pragma unroll
      for (int j = 0; j < 4; ++j) ov[j] = f2bf(o[j]);
      *(us4*)&obf[(long)row * 512 + idx] = ov;
    }
    if (obf2) {
      const f32x4 a2 = *(const f32x4*)&add2[(long)row * 512 + idx];
      us4 ov;
#pragma unroll
      for (int j = 0; j < 4; ++j) ov[j] = f2bf(o[j] + a2[j]);
      *(us4*)&obf2[(long)row * 512 + idx] = ov;
    }
  }
}

// Fused last-layer LN3 + final LN (both row-local): out = LN_f(LN3(a + res))
__global__ __launch_bounds__(256) void ln512_last(const float* a, const float* res,
                                                  const float* g1, const float* b1,
                                                  const float* g2, const float* b2,
                                                  float* out) {
  const int row = blockIdx.x * 4 + (threadIdx.x >> 6);
  const int lane = threadIdx.x & 63;
  f32x4 x[2];
#pragma unroll
  for (int i = 0; i < 2; ++i) {
    const int idx = (i * 64 + lane) * 4;
    x[i] = *(const f32x4*)&a[(long)row * 512 + idx];
    x[i] += *(const f32x4*)&res[(long)row * 512 + idx];
  }
  // LN3
  float s = 0.f;
#pragma unroll
  for (int i = 0; i < 2; ++i)
#pragma unroll
    for (int j = 0; j < 4; ++j) s += x[i][j];
  float mean = wred_sum(s) * (1.0f / 512.0f);
  float vv = 0.f;
#pragma unroll
  for (int i = 0; i < 2; ++i)
#pragma unroll
    for (int j = 0; j < 4; ++j) { const float d = x[i][j] - mean; vv += d * d; }
  vv = wred_sum(vv) * (1.0f / 512.0f);
  float rs = rsqrtf(vv + 1e-5f);
  f32x4 o[2];
#pragma unroll
  for (int i = 0; i < 2; ++i) {
    const int idx = (i * 64 + lane) * 4;
    const f32x4 gv = *(const f32x4*)&g1[idx];
    const f32x4 bv = *(const f32x4*)&b1[idx];
#pragma unroll
    for (int j = 0; j < 4; ++j) o[i][j] = (x[i][j] - mean) * rs * gv[j] + bv[j];
  }
  // final LN on o
  s = 0.f;
#pragma unroll
  for (int i = 0; i < 2; ++i)
#pragma unroll
    for (int j = 0; j < 4; ++j) s += o[i][j];
  mean = wred_sum(s) * (1.0f / 512.0f);
  vv = 0.f;
#pragma unroll
  for (int i = 0; i < 2; ++i)
#pragma unroll
    for (int j = 0; j < 4; ++j) { const float d = o[i][j] - mean; vv += d * d; }
  vv = wred_sum(vv) * (1.0f / 512.0f);
  rs = rsqrtf(vv + 1e-5f);
#pragma unroll
  for (int i = 0; i < 2; ++i) {
    const int idx = (i * 64 + lane) * 4;
    const f32x4 gv = *(const f32x4*)&g2[idx];
    const f32x4 bv = *(const f32x4*)&b2[idx];
    f32x4 ov;
#pragma unroll
    for (int j = 0; j < 4; ++j) ov[j] = (o[i][j] - mean) * rs * gv[j] + bv[j];
    *(f32x4*)&out[(long)row * 512 + idx] = ov;
  }
}

// ---------------------------------------------------------------------------
// single segmented converter: 5 plain segs + 2 dual segs (a->bf16, a+b->bf16)
// ---------------------------------------------------------------------------
struct CvtSeg { const float* s; const float* s2; u16* d; u16* d2; int nblk; int dual; };
struct CvtAll { CvtSeg seg[7]; };
__global__ __launch_bounds__(256) void cvt_all(CvtAll c) {
  int b = blockIdx.x, si = 0;
  while (si < 6 && b >= c.seg[si].nblk) { b -= c.seg[si].nblk; ++si; }
  const CvtSeg sg = c.seg[si];
  const long i = ((long)b * 256 + threadIdx.x) * 8;
  f32x4 a0 = *(const f32x4*)&sg.s[i], a1 = *(const f32x4*)&sg.s[i + 4];
  short8 o1;
#pragma unroll
  for (int k = 0; k < 4; ++k) { o1[k] = (short)f2bf(a0[k]); o1[k + 4] = (short)f2bf(a1[k]); }
  *(short8*)&sg.d[i] = o1;
  if (sg.dual) {
    f32x4 b0 = *(const f32x4*)&sg.s2[i], b1 = *(const f32x4*)&sg.s2[i + 4];
    short8 o2;
#pragma unroll
    for (int k = 0; k < 4; ++k) {
      o2[k] = (short)f2bf(a0[k] + b0[k]);
      o2[k + 4] = (short)f2bf(a1[k] + b1[k]);
    }
    *(short8*)&sg.d2[i] = o2;
  }
}

// ---------------------------------------------------------------------------
// custom attention small kernels (fp32)
// ---------------------------------------------------------------------------
// partial sums of (x1+qpos) over 32-n chunks: xp[b*32+c][512]
__global__ __launch_bounds__(256) void xsum1(const float* x1, const float* qpos, float* xp) {
  const int u = blockIdx.x, b = u >> 5, c = u & 31, tid = threadIdx.x;
  float a0 = 0.f, a1 = 0.f;
  for (int n = c * 32; n < c * 32 + 32; ++n) {
    const long i0 = ((long)(n * 2 + b)) * 512;
    a0 += x1[i0 + tid] + qpos[i0 + tid];
    a1 += x1[i0 + 256 + tid] + qpos[i0 + 256 + tid];
  }
  xp[(long)u * 512 + tid] = a0;
  xp[(long)u * 512 + 256 + tid] = a1;
}

// inline xsum reduce + qs GEMV + s1[z][m] = 0.125*sum_d qs[d]*kT[b][d*8+h][m]
__global__ __launch_bounds__(256) void s1_k(const float* xp, const float* W0, const float* b0,
                                            const float* kT, float* s1) {
  const int z = blockIdx.x, mc = blockIdx.y, b = z >> 3, h = z & 7;
  const int tid = threadIdx.x;
  __shared__ float xsl[512];
  __shared__ float part[4][64];
  __shared__ float qsl[64];
#pragma unroll
  for (int dh = 0; dh < 2; ++dh) {
    const int d = dh * 256 + tid;
    float s = 0.f;
#pragma unroll
    for (int c = 0; c < 32; ++c) s += xp[((long)b * 32 + c) * 512 + d];
    xsl[d] = s;
  }
  __syncthreads();
  const int dd = tid & 63, qd = tid >> 6;
  const int ch = dd * 8 + h;
  float pp = 0.f;
  const float* wrp = W0 + (long)ch * 512 + qd * 128;
#pragma unroll 8
  for (int i = 0; i < 128; ++i) pp += wrp[i] * xsl[qd * 128 + i];
  part[qd][dd] = pp;
  __syncthreads();
  if (tid < 64)
    qsl[tid] = part[0][tid] + part[1][tid] + part[2][tid] + part[3][tid]
               + 1024.0f * b0[tid * 8 + h];
  __syncthreads();
  const int m = mc * 256 + tid;
  float a = 0.f;
#pragma unroll 8
  for (int d2 = 0; d2 < 64; ++d2)
    a += qsl[d2] * kT[((long)b * 512 + d2 * 8 + h) * 2048 + m];
  s1[(long)z * 2048 + m] = 0.125f * a;
}

// per (z, nchunk of 4): softmax rows, accumulate mw[n]-weighted probs -> partials
__global__ __launch_bounds__(256) void pw_k(const float* kT, const float* s1,
                                            const float* mw, float* pwpart) {
  const int z = blockIdx.x & 15, c = blockIdx.x >> 4;
  const int b = z >> 3, h = z & 7;
  const int tid = threadIdx.x, lane = tid & 63, wid = tid >> 6;
  __shared__ float redm[4], reds[4];
  float s1v[8], pwa[8];
#pragma unroll
  for (int i = 0; i < 8; ++i) { s1v[i] = s1[(long)z * 2048 + tid + i * 256]; pwa[i] = 0.f; }
  for (int n = c * 4; n < c * 4 + 4; ++n) {
    const float* kr = kT + ((long)b * 512 + n * 8 + h) * 2048;
    float sv[8];
    float mx = -3e38f;
#pragma unroll
    for (int i = 0; i < 8; ++i) { sv[i] = kr[tid + i * 256] * s1v[i]; mx = fmaxf(mx, sv[i]); }
    mx = wred_max(mx);
    if (lane == 0) redm[wid] = mx;
    __syncthreads();
    mx = fmaxf(fmaxf(redm[0], redm[1]), fmaxf(redm[2], redm[3]));
    float sm = 0.f;
#pragma unroll
    for (int i = 0; i < 8; ++i) { sv[i] = __expf(sv[i] - mx); sm += sv[i]; }
    sm = wred_sum(sm);
    if (lane == 0) reds[wid] = sm;
    __syncthreads();
    sm = reds[0] + reds[1] + reds[2] + reds[3];
    const float wnl = mw[n] / sm;
#pragma unroll
    for (int i = 0; i < 8; ++i) pwa[i] += wnl * sv[i];
    __syncthreads();
  }
#pragma unroll
  for (int i = 0; i < 8; ++i)
    pwpart[((long)c * 16 + z) * 2048 + tid + i * 256] = pwa[i];
}

// t2c[b][d*8+h] = sum_m vT[b][d*8+h][m] * (sum_c pwpart[c][z][m]) + mb
__global__ __launch_bounds__(256) void x2_k(const float* vT, const float* pwpart,
                                            const float* mb, float* t2c) {
  const int z = blockIdx.x, b = z >> 3, h = z & 7;
  const int tid = threadIdx.x, lane = tid & 63, wid = tid >> 6;
  float pwv[32];
#pragma unroll 4
  for (int i = 0; i < 32; ++i) {
    const int m = lane + i * 64;
    float s = 0.f;
#pragma unroll
    for (int c = 0; c < 16; ++c) s += pwpart[((long)c * 16 + z) * 2048 + m];
    pwv[i] = s;
  }
#pragma unroll
  for (int ci = 0; ci < 4; ++ci) {
    const int d = wid * 16 + blockIdx.y * 4 + ci, ch = d * 8 + h;
    const float* vr = vT + ((long)b * 512 + ch) * 2048;
    float acc = 0.f;
#pragma unroll 8
    for (int i = 0; i < 32; ++i) acc += vr[lane + i * 64] * pwv[i];
    acc = wred_sum(acc);
    if (lane == 0) t2c[b * 512 + ch] = acc + mb[0];
  }
}

// ---------------------------------------------------------------------------
extern "C" void kernel_launch(void* const* d_in, const int* in_sizes, int n_in,
                              void* d_out, int out_size, void* d_ws, size_t ws_size,
                              hipStream_t stream) {
  (void)in_sizes; (void)n_in; (void)out_size; (void)ws_size;
  const float* tgt   = (const float*)d_in[0];
  const float* memry = (const float*)d_in[1];
  const float* qpos  = (const float*)d_in[2];
  const float* pos   = (const float*)d_in[3];
  const float* ipw   = (const float*)d_in[4];
  const float* ipb   = (const float*)d_in[5];
  const float* outw  = (const float*)d_in[6];
  const float* outb  = (const float*)d_in[7];
  const float* convw = (const float*)d_in[8];
  const float* convb = (const float*)d_in[9];
  const float* mlpw  = (const float*)d_in[10];
  const float* mlpb  = (const float*)d_in[11];
  const float* l1w   = (const float*)d_in[12];
  const float* l1b   = (const float*)d_in[13];
  const float* l2w   = (const float*)d_in[14];
  const float* l2b   = (const float*)d_in[15];
  const float* lng   = (const float*)d_in[16];
  const float* lnbp  = (const float*)d_in[17];
  const float* fg    = (const float*)d_in[18];
  const float* fbv   = (const float*)d_in[19];

  char* base = (char*)d_ws;
  const long MBy = 1 << 20;
  u16*   qkb   = (u16*)(base + 0);            // 4MB
  u16*   Vtb   = (u16*)(base + 4 * MBy);      // 2MB
  u16*   aob   = (u16*)(base + 6 * MBy);      // 2MB
  u16*   xb    = (u16*)(base + 8 * MBy);      // 2MB
  u16*   xqb   = (u16*)(base + 10 * MBy);     // 2MB
  u16*   mempb = (u16*)(base + 12 * MBy);     // 4MB (memory+pos bf16)
  u16*   memb  = (u16*)(base + 16 * MBy);     // 4MB (memory bf16) -- adjacent!
  u16*   x2nb  = (u16*)(base + 20 * MBy);     // 2MB
  u16*   hb    = (u16*)(base + 22 * MBy);     // 8MB
  float* t2    = (float*)(base + 30 * MBy);   // 4MB
  float* x1    = (float*)(base + 34 * MBy);   // 4MB
  float* x2n   = (float*)(base + 38 * MBy);   // 4MB
  float* fbuf  = (float*)(base + 42 * MBy);   // 4MB
  float* xbuf  = (float*)(base + 46 * MBy);   // 4MB
  u16*   ipwb  = (u16*)(base + 50 * MBy);     // 6MB
  u16*   outwb = (u16*)(base + 56 * MBy);     // 2MB
  u16*   convwb= (u16*)(base + 58 * MBy);     // 6MB
  u16*   l1wb  = (u16*)(base + 64 * MBy);     // 8MB
  u16*   l2wb  = (u16*)(base + 72 * MBy);     // 8MB
  float* xpart = (float*)(base + 80 * MBy);               // 128KB
  float* s1b   = (float*)(base + 80 * MBy + 256 * 1024);  // 128KB
  float* pwpart= (float*)(base + 81 * MBy);               // 2MB
  float* t2c   = (float*)(base + 83 * MBy);               // 4KB
  float* kvall = (float*)(base + 96 * MBy);               // 64MB [16][512][2048]

  // one-time conversions (single launch) + ALL-layer conv k/v projections
  {
    CvtAll c;
    c.seg[0] = { ipw,   nullptr, ipwb,  nullptr, 1536, 0 };
    c.seg[1] = { outw,  nullptr, outwb, nullptr,  512, 0 };
    c.seg[2] = { convw, nullptr, convwb,nullptr, 1536, 0 };
    c.seg[3] = { l1w,   nullptr, l1wb,  nullptr, 2048, 0 };
    c.seg[4] = { l2w,   nullptr, l2wb,  nullptr, 2048, 0 };
    c.seg[5] = { memry, pos,     memb,  mempb,   1024, 1 };
    c.seg[6] = { tgt,   qpos,    xb,    xqb,      512, 1 };
    cvt_all<<<dim3(9216), dim3(256), 0, stream>>>(c);
  }
  convkv_k<<<dim3(1024), dim3(256), 0, stream>>>(mempb, convwb, convb, kvall);

  for (int l = 0; l < 4; ++l) {
    const float* xin = l ? xbuf : tgt;
    const float* kT = kvall + (long)l * 4194304;
    const float* vT = kT + 2097152;

    // A: grouped qk-proj + v-proj (64x64 tiles, 768 blocks)
    {
      GemmP q{};
      q.A = xqb; q.lda = 512; q.B = ipwb + (long)l * 786432; q.ldb = 512;
      q.C = qkb; q.crs = 1024; q.ccs = 1; q.cbf16 = 1;
      q.bias = ipb + (long)l * 1536;
      q.K = 512; q.azi = q.bzi = q.czi = 1; q.scale = 1.0f;
      GemmP v{};
      v.A = xb; v.lda = 512; v.B = ipwb + (long)l * 786432 + 524288; v.ldb = 512;
      v.C = Vtb; v.cm = 1; v.bias = ipb + (long)l * 1536 + 1024;
      v.K = 512; v.azi = v.bzi = v.czi = 1; v.scale = 1.0f;
      qkv2_k<<<dim3(768), dim3(256), 0, stream>>>(q, v);
    }
    // B: flash attention
    flash_attn<<<dim3(16, 16), dim3(256), 0, stream>>>(qkb, Vtb, aob);
    // C: out projection
    {
      GemmP o{};
      o.A = aob; o.lda = 512; o.B = outwb + (long)l * 262144; o.ldb = 512;
      o.C = t2; o.crs = 512; o.ccs = 1; o.bias = outb + l * 512;
      o.K = 512; o.azi = o.bzi = o.czi = 1; o.scale = 1.0f;
      gemm_k<32, 64><<<dim3(8, 64, 1), dim3(256), 0, stream>>>(o);
    }
    // D: LN1
    ln512<<<dim3(512), dim3(256), 0, stream>>>(t2, xin, 1, lng + (l * 3) * 512,
                                               lnbp + (l * 3) * 512, x1, nullptr,
                                               nullptr, nullptr);
    // E-H: custom attention
    xsum1<<<dim3(64), dim3(256), 0, stream>>>(x1, qpos, xpart);
    s1_k<<<dim3(16, 8), dim3(256), 0, stream>>>(xpart, convw + ((long)l * 3) * 262144,
                                                convb + (l * 3) * 512, kT, s1b);
    pw_k<<<dim3(256), dim3(256), 0, stream>>>(kT, s1b, mlpw + l * 64, pwpart);
    x2_k<<<dim3(16, 4), dim3(256), 0, stream>>>(vT, pwpart, mlpb + l, t2c);
    // I: LN2
    ln512<<<dim3(512), dim3(256), 0, stream>>>(x1, t2c, 2, lng + (l * 3 + 1) * 512,
                                               lnbp + (l * 3 + 1) * 512, x2n, x2nb,
                                               nullptr, nullptr);
    // J: FFN1 (64x64 tiles)
    {
      GemmP f1{};
      f1.A = x2nb; f1.lda = 512; f1.B = l1wb + (long)l * 1048576; f1.ldb = 512;
      f1.C = hb; f1.crs = 2048; f1.ccs = 1; f1.cbf16 = 1; f1.relu = 1;
      f1.bias = l1b + l * 2048;
      f1.K = 512; f1.azi = f1.bzi = f1.czi = 1; f1.scale = 1.0f;
      gemm_k<64, 64><<<dim3(32, 32, 1), dim3(256), 0, stream>>>(f1);
    }
    // K: FFN2
    {
      GemmP f2{};
      f2.A = hb; f2.lda = 2048; f2.B = l2wb + (long)l * 1048576; f2.ldb = 2048;
      f2.C = fbuf; f2.crs = 512; f2.ccs = 1; f2.bias = l2b + l * 512;
      f2.K = 2048; f2.azi = f2.bzi = f2.czi = 1; f2.scale = 1.0f;
      gemm_k<32, 64><<<dim3(8, 64, 1), dim3(256), 0, stream>>>(f2);
    }
    // L: LN3 (+ next layer's xb/xqb bf16) — fused with final LN on last layer
    if (l < 3) {
      ln512<<<dim3(512), dim3(256), 0, stream>>>(fbuf, x2n, 1, lng + (l * 3 + 2) * 512,
                                                 lnbp + (l * 3 + 2) * 512, xbuf, xb,
                                                 qpos, xqb);
    } else {
      ln512_last<<<dim3(512), dim3(256), 0, stream>>>(fbuf, x2n,
                                                      lng + (l * 3 + 2) * 512,
                                                      lnbp + (l * 3 + 2) * 512,
                                                      fg, fbv, (float*)d_out);
    }
  }
}

// Round 11
// 564.743 us; speedup vs baseline: 1.0169x; 1.0169x over previous
//
#include <hip/hip_runtime.h>
#include <cstdint>

typedef __attribute__((ext_vector_type(8))) short short8;
typedef __attribute__((ext_vector_type(4))) float f32x4;
typedef __attribute__((ext_vector_type(4))) unsigned short us4;
typedef unsigned short u16;

static __device__ __forceinline__ u16 f2bf(float f) {
  union { float f; unsigned u; } x; x.f = f;
  return (u16)((x.u + 0x7FFFu + ((x.u >> 16) & 1u)) >> 16);
}

static __device__ __forceinline__ float wred_max(float v) {
#pragma unroll
  for (int o = 32; o > 0; o >>= 1) v = fmaxf(v, __shfl_xor(v, o, 64));
  return v;
}
static __device__ __forceinline__ float wred_sum(float v) {
#pragma unroll
  for (int o = 32; o > 0; o >>= 1) v += __shfl_xor(v, o, 64);
  return v;
}

static __device__ __forceinline__ void gload16(const void* g, void* l) {
  __builtin_amdgcn_global_load_lds(
      (const __attribute__((address_space(1))) unsigned int*)g,
      (__attribute__((address_space(3))) unsigned int*)l, 16, 0, 0);
}

// ---------------------------------------------------------------------------
// bf16 MFMA GEMM body. A[M][K] bf16, Bt[N][K] bf16.
// cm=1: Vtb transpose-split epilogue (row rw = n*2+b composite).
// ---------------------------------------------------------------------------
struct GemmP {
  const u16* A; const u16* B; void* C; const float* bias;
  int K, lda, ldb, crs, ccs;
  int azi, bzi, czi, biasdz;
  long aso, asi, bso, bsi, cso, csi, biassz;
  float scale; int relu; int cbf16; int cm;
};

template<int ROWS>
static __device__ __forceinline__ void stage_t(const u16* g, int ld, u16* lds,
                                               int w, int lane) {
#pragma unroll
  for (int j = 0; j < ROWS / 32; ++j) {
    const int idx = w * (ROWS / 32) + j;
    const int r = idx * 8 + (lane >> 3);
    const int gc = ((lane & 7) ^ (r & 7)) * 8;  // swizzled 16B granule
    gload16(g + (long)r * ld + gc, lds + idx * 512);
  }
}

template<int BM, int BN>
static __device__ void gbody(const GemmP& p, int tm, int tn, int z, u16* Al, u16* Bl) {
  constexpr int WTM = BM / 2, WTN = BN / 2;
  constexpr int FM = WTM / 16, FN = WTN / 16;
  const int tid = threadIdx.x, lane = tid & 63, w = tid >> 6;
  const int wr = w >> 1, wc = w & 1, lr = lane & 15, lk4 = lane >> 4;
  const long ab = (long)(z / p.azi) * p.aso + (long)(z % p.azi) * p.asi + (long)tm * p.lda;
  const long bb = (long)(z / p.bzi) * p.bso + (long)(z % p.bzi) * p.bsi + (long)tn * p.ldb;
  const long cb = (long)(z / p.czi) * p.cso + (long)(z % p.czi) * p.csi;
  const long boff = p.biasdz ? (long)(z / p.biasdz) * p.biassz : 0;

  f32x4 acc[FM][FN];
#pragma unroll
  for (int i = 0; i < FM; ++i)
#pragma unroll
    for (int j = 0; j < FN; ++j) acc[i][j] = (f32x4)(0.0f);

  const u16* Ag = p.A + ab;
  const u16* Bg = p.B + bb;
  stage_t<BM>(Ag, p.lda, Al, w, lane);
  stage_t<BN>(Bg, p.ldb, Bl, w, lane);
  __syncthreads();

  const int nt = p.K >> 6;
  for (int t = 0; t < nt; ++t) {
    const int cur = t & 1;
    if (t + 1 < nt) {
      stage_t<BM>(Ag + (long)(t + 1) * 64, p.lda, Al + (cur ^ 1) * BM * 64, w, lane);
      stage_t<BN>(Bg + (long)(t + 1) * 64, p.ldb, Bl + (cur ^ 1) * BN * 64, w, lane);
    }
    short8 af[FM][2], bfv[FN][2];
#pragma unroll
    for (int ks = 0; ks < 2; ++ks) {
#pragma unroll
      for (int mi = 0; mi < FM; ++mi) {
        const int row = wr * WTM + mi * 16 + lr;
        const int off = row * 128 + ((ks * 4 + lk4) ^ (row & 7)) * 16;
        af[mi][ks] = *(const short8*)((const char*)(Al + cur * BM * 64) + off);
      }
#pragma unroll
      for (int ni = 0; ni < FN; ++ni) {
        const int row = wc * WTN + ni * 16 + lr;
        const int off = row * 128 + ((ks * 4 + lk4) ^ (row & 7)) * 16;
        bfv[ni][ks] = *(const short8*)((const char*)(Bl + cur * BN * 64) + off);
      }
    }
#pragma unroll
    for (int ks = 0; ks < 2; ++ks)
#pragma unroll
      for (int mi = 0; mi < FM; ++mi)
#pragma unroll
        for (int ni = 0; ni < FN; ++ni)
          acc[mi][ni] = __builtin_amdgcn_mfma_f32_16x16x32_bf16(af[mi][ks], bfv[ni][ks],
                                                                acc[mi][ni], 0, 0, 0);
    __syncthreads();
  }

  const int kg = lk4 * 4;
#pragma unroll
  for (int ni = 0; ni < FN; ++ni) {
    const int col = tn + wc * WTN + ni * 16 + lr;
    const float bv = p.bias ? p.bias[boff + col] : 0.0f;
#pragma unroll
    for (int mi = 0; mi < FM; ++mi) {
      const int rb = tm + wr * WTM + mi * 16 + kg;
#pragma unroll
      for (int r = 0; r < 4; ++r) {
        const int rw = rb + r;
        float v = acc[mi][ni][r] * p.scale + bv;
        if (p.relu) v = fmaxf(v, 0.0f);
        if (p.cm) {
          const long ci = (long)(rw & 1) * 524288 + (long)col * 1024 + (rw >> 1);
          ((u16*)p.C)[ci] = f2bf(v);
        } else {
          const long ci = cb + (long)rw * p.crs + (long)col * p.ccs;
          if (p.cbf16) ((u16*)p.C)[ci] = f2bf(v);
          else ((float*)p.C)[ci] = v;
        }
      }
    }
  }
}

template<int BM, int BN>
__global__ __launch_bounds__(256, 4) void gemm_k(GemmP p) {
  __shared__ __align__(16) u16 Al[2 * BM * 64];
  __shared__ __align__(16) u16 Bl[2 * BN * 64];
  gbody<BM, BN>(p, blockIdx.y * BM, blockIdx.x * BN, blockIdx.z, Al, Bl);
}

// grouped qk-proj (512 tiles of 64x64) + v-proj (256 tiles of 64x64, cm epilogue)
__global__ __launch_bounds__(256, 4) void qkv2_k(GemmP q, GemmP v) {
  __shared__ __align__(16) u16 Al[2 * 64 * 64];
  __shared__ __align__(16) u16 Bl[2 * 64 * 64];
  const int id = blockIdx.x;
  if (id < 512) gbody<64, 64>(q, (id / 16) * 64, (id % 16) * 64, 0, Al, Bl);
  else { const int u = id - 512; gbody<64, 64>(v, (u / 8) * 64, (u % 8) * 64, 0, Al, Bl); }
}

// ALL-layer conv k/v projections: 128x128 tiles. z = l*4 + g*2 + b
__global__ __launch_bounds__(256, 2) void convkv_k(const u16* mempb, const u16* convwb,
                                                   const float* convb, float* kvall) {
  __shared__ __align__(16) u16 Al[2 * 128 * 64];
  __shared__ __align__(16) u16 Bl[2 * 128 * 64];
  const int id = blockIdx.x;
  const int z = id >> 6, rr = id & 63;
  const int l = z >> 2, g = (z >> 1) & 1, b = z & 1;
  GemmP p{};
  p.A = mempb + g * 2097152 + b * 512; p.lda = 1024;
  p.B = convwb + ((long)(l * 3 + 1 + g)) * 262144; p.ldb = 512;
  p.C = kvall + (long)z * 1048576; p.crs = 1; p.ccs = 2048;
  p.bias = convb + (l * 3 + 1 + g) * 512;
  p.K = 512; p.azi = p.bzi = p.czi = 1; p.scale = 1.0f;
  gbody<128, 128>(p, (rr >> 2) * 128, (rr & 3) * 128, 0, Al, Bl);
}

// ---------------------------------------------------------------------------
// Fused flash attention
// ---------------------------------------------------------------------------
__global__ __launch_bounds__(256) void flash_attn(const u16* qkb, const u16* Vtb, u16* aob) {
  const int zh = blockIdx.x, b = zh >> 3, h = zh & 7;
  const int qt = blockIdx.y;
  const int tid = threadIdx.x, lane = tid & 63, w = tid >> 6;
  const int lr = lane & 15, g = lane >> 4;

  __shared__ __align__(16) u16 Kl[2][64 * 64];
  __shared__ __align__(16) u16 Vl[2][64 * 64];
  __shared__ __align__(16) u16 Pl[4][16 * 64];

  const int nrow = qt * 64 + w * 16 + lr;
  const long qbase = ((long)(nrow * 2 + b)) * 1024 + h * 64;
  const short8 q0 = *(const short8*)&qkb[qbase + g * 8];
  const short8 q1 = *(const short8*)&qkb[qbase + 32 + g * 8];

  f32x4 acc_o[4];
#pragma unroll
  for (int i = 0; i < 4; ++i) acc_o[i] = (f32x4)(0.0f);
  float m_run = -3e38f, l_run = 0.0f;

  auto stg = [&](int buf, int t) {
    const int m0 = t * 64;
#pragma unroll
    for (int j = 0; j < 2; ++j) {
      const int c = w * 2 + j;
      const int row = c * 8 + (lane >> 3);
      const int src = (lane & 7) ^ (row & 7);
      gload16(qkb + ((long)((m0 + row) * 2 + b)) * 1024 + 512 + h * 64 + src * 8,
              &Kl[buf][c * 512]);
      gload16(Vtb + (long)b * 524288 + ((long)(h * 64 + row)) * 1024 + m0 + src * 8,
              &Vl[buf][c * 512]);
    }
  };

  stg(0, 0);
  __syncthreads();

  for (int t = 0; t < 16; ++t) {
    const int cur = t & 1;
    if (t < 15) stg(cur ^ 1, t + 1);

    f32x4 s_acc[4];
#pragma unroll
    for (int ks = 0; ks < 4; ++ks) {
      const int krow = ks * 16 + lr;
      const short8 k0 = *(const short8*)&Kl[cur][krow * 64 + ((g ^ (krow & 7)) * 8)];
      const short8 k1 = *(const short8*)&Kl[cur][krow * 64 + (((4 + g) ^ (krow & 7)) * 8)];
      f32x4 z4 = (f32x4)(0.0f);
      z4 = __builtin_amdgcn_mfma_f32_16x16x32_bf16(k0, q0, z4, 0, 0, 0);
      z4 = __builtin_amdgcn_mfma_f32_16x16x32_bf16(k1, q1, z4, 0, 0, 0);
      s_acc[ks] = z4;
    }

    float mx = -3e38f;
#pragma unroll
    for (int ks = 0; ks < 4; ++ks)
#pragma unroll
      for (int r = 0; r < 4; ++r) mx = fmaxf(mx, s_acc[ks][r]);
    mx = fmaxf(mx, __shfl_xor(mx, 16, 64));
    mx = fmaxf(mx, __shfl_xor(mx, 32, 64));
    mx *= 0.125f;
    const float m_new = fmaxf(m_run, mx);
    const float alpha = __expf(m_run - m_new);
    float psum = 0.0f;
    u16 pb[4][4];
#pragma unroll
    for (int ks = 0; ks < 4; ++ks)
#pragma unroll
      for (int r = 0; r < 4; ++r) {
        const float pv = __expf(s_acc[ks][r] * 0.125f - m_new);
        psum += pv;
        pb[ks][r] = f2bf(pv);
      }
    psum += __shfl_xor(psum, 16, 64);
    psum += __shfl_xor(psum, 32, 64);
    l_run = l_run * alpha + psum;
    m_run = m_new;
#pragma unroll
    for (int i = 0; i < 4; ++i) acc_o[i] *= alpha;

#pragma unroll
    for (int ks = 0; ks < 4; ++ks)
#pragma unroll
      for (int r = 0; r < 4; ++r) {
        const int m = ks * 16 + g * 4 + r;
        Pl[w][lr * 64 + (((m >> 3) ^ (lr & 7)) * 8) + (m & 7)] = pb[ks][r];
      }

#pragma unroll
    for (int mh = 0; mh < 2; ++mh) {
      const short8 pt = *(const short8*)&Pl[w][lr * 64 + (((mh * 4 + g) ^ (lr & 7)) * 8)];
#pragma unroll
      for (int ds = 0; ds < 4; ++ds) {
        const int drow = ds * 16 + lr;
        const short8 vt = *(const short8*)&Vl[cur][drow * 64 + (((mh * 4 + g) ^ (drow & 7)) * 8)];
        acc_o[ds] = __builtin_amdgcn_mfma_f32_16x16x32_bf16(vt, pt, acc_o[ds], 0, 0, 0);
      }
    }
    __syncthreads();
  }

  const float invl = 1.0f / l_run;
#pragma unroll
  for (int ds = 0; ds < 4; ++ds)
#pragma unroll
    for (int r = 0; r < 4; ++r) {
      const int d = ds * 16 + g * 4 + r;
      aob[((long)(nrow * 2 + b)) * 512 + h * 64 + d] = f2bf(acc_o[ds][r] * invl);
    }
}

// ---------------------------------------------------------------------------
// LayerNorm D=512; resmode 0/1/2; optional bf16 out; optional bf16(out+add2)
// ---------------------------------------------------------------------------
__global__ __launch_bounds__(256) void ln512(const float* a, const float* res, int resmode,
                                             const float* g, const float* bt,
                                             float* out, u16* obf,
                                             const float* add2, u16* obf2) {
  const int row = blockIdx.x * 4 + (threadIdx.x >> 6);
  const int lane = threadIdx.x & 63;
  const float* ar = a + (long)row * 512;
  f32x4 x[2];
#pragma unroll
  for (int i = 0; i < 2; ++i) {
    const int idx = (i * 64 + lane) * 4;
    x[i] = *(const f32x4*)&ar[idx];
    if (resmode == 1) x[i] += *(const f32x4*)&res[(long)row * 512 + idx];
    else if (resmode == 2) x[i] += *(const f32x4*)&res[(row & 1) * 512 + idx];
  }
  float s = 0.f;
#pragma unroll
  for (int i = 0; i < 2; ++i)
#pragma unroll
    for (int j = 0; j < 4; ++j) s += x[i][j];
  const float mean = wred_sum(s) * (1.0f / 512.0f);
  float vv = 0.f;
#pragma unroll
  for (int i = 0; i < 2; ++i)
#pragma unroll
    for (int j = 0; j < 4; ++j) { const float d = x[i][j] - mean; vv += d * d; }
  vv = wred_sum(vv) * (1.0f / 512.0f);
  const float rs = rsqrtf(vv + 1e-5f);
#pragma unroll
  for (int i = 0; i < 2; ++i) {
    const int idx = (i * 64 + lane) * 4;
    const f32x4 gv = *(const f32x4*)&g[idx];
    const f32x4 bv = *(const f32x4*)&bt[idx];
    f32x4 o;
#pragma unroll
    for (int j = 0; j < 4; ++j) o[j] = (x[i][j] - mean) * rs * gv[j] + bv[j];
    *(f32x4*)&out[(long)row * 512 + idx] = o;
    if (obf) {
      us4 ov;
#pragma unroll
      for (int j = 0; j < 4; ++j) ov[j] = f2bf(o[j]);
      *(us4*)&obf[(long)row * 512 + idx] = ov;
    }
    if (obf2) {
      const f32x4 a2 = *(const f32x4*)&add2[(long)row * 512 + idx];
      us4 ov;
#pragma unroll
      for (int j = 0; j < 4; ++j) ov[j] = f2bf(o[j] + a2[j]);
      *(us4*)&obf2[(long)row * 512 + idx] = ov;
    }
  }
}

// Fused last-layer LN3 + final LN (both row-local): out = LN_f(LN3(a + res))
__global__ __launch_bounds__(256) void ln512_last(const float* a, const float* res,
                                                  const float* g1, const float* b1,
                                                  const float* g2, const float* b2,
                                                  float* out) {
  const int row = blockIdx.x * 4 + (threadIdx.x >> 6);
  const int lane = threadIdx.x & 63;
  f32x4 x[2];
#pragma unroll
  for (int i = 0; i < 2; ++i) {
    const int idx = (i * 64 + lane) * 4;
    x[i] = *(const f32x4*)&a[(long)row * 512 + idx];
    x[i] += *(const f32x4*)&res[(long)row * 512 + idx];
  }
  // LN3
  float s = 0.f;
#pragma unroll
  for (int i = 0; i < 2; ++i)
#pragma unroll
    for (int j = 0; j < 4; ++j) s += x[i][j];
  float mean = wred_sum(s) * (1.0f / 512.0f);
  float vv = 0.f;
#pragma unroll
  for (int i = 0; i < 2; ++i)
#pragma unroll
    for (int j = 0; j < 4; ++j) { const float d = x[i][j] - mean; vv += d * d; }
  vv = wred_sum(vv) * (1.0f / 512.0f);
  float rs = rsqrtf(vv + 1e-5f);
  f32x4 o[2];
#pragma unroll
  for (int i = 0; i < 2; ++i) {
    const int idx = (i * 64 + lane) * 4;
    const f32x4 gv = *(const f32x4*)&g1[idx];
    const f32x4 bv = *(const f32x4*)&b1[idx];
#pragma unroll
    for (int j = 0; j < 4; ++j) o[i][j] = (x[i][j] - mean) * rs * gv[j] + bv[j];
  }
  // final LN on o
  s = 0.f;
#pragma unroll
  for (int i = 0; i < 2; ++i)
#pragma unroll
    for (int j = 0; j < 4; ++j) s += o[i][j];
  mean = wred_sum(s) * (1.0f / 512.0f);
  vv = 0.f;
#pragma unroll
  for (int i = 0; i < 2; ++i)
#pragma unroll
    for (int j = 0; j < 4; ++j) { const float d = o[i][j] - mean; vv += d * d; }
  vv = wred_sum(vv) * (1.0f / 512.0f);
  rs = rsqrtf(vv + 1e-5f);
#pragma unroll
  for (int i = 0; i < 2; ++i) {
    const int idx = (i * 64 + lane) * 4;
    const f32x4 gv = *(const f32x4*)&g2[idx];
    const f32x4 bv = *(const f32x4*)&b2[idx];
    f32x4 ov;
#pragma unroll
    for (int j = 0; j < 4; ++j) ov[j] = (o[i][j] - mean) * rs * gv[j] + bv[j];
    *(f32x4*)&out[(long)row * 512 + idx] = ov;
  }
}

// ---------------------------------------------------------------------------
// single segmented converter: 5 plain segs + 2 dual segs (a->bf16, a+b->bf16)
// ---------------------------------------------------------------------------
struct CvtSeg { const float* s; const float* s2; u16* d; u16* d2; int nblk; int dual; };
struct CvtAll { CvtSeg seg[7]; };
__global__ __launch_bounds__(256) void cvt_all(CvtAll c) {
  int b = blockIdx.x, si = 0;
  while (si < 6 && b >= c.seg[si].nblk) { b -= c.seg[si].nblk; ++si; }
  const CvtSeg sg = c.seg[si];
  const long i = ((long)b * 256 + threadIdx.x) * 8;
  f32x4 a0 = *(const f32x4*)&sg.s[i], a1 = *(const f32x4*)&sg.s[i + 4];
  short8 o1;
#pragma unroll
  for (int k = 0; k < 4; ++k) { o1[k] = (short)f2bf(a0[k]); o1[k + 4] = (short)f2bf(a1[k]); }
  *(short8*)&sg.d[i] = o1;
  if (sg.dual) {
    f32x4 b0 = *(const f32x4*)&sg.s2[i], b1 = *(const f32x4*)&sg.s2[i + 4];
    short8 o2;
#pragma unroll
    for (int k = 0; k < 4; ++k) {
      o2[k] = (short)f2bf(a0[k] + b0[k]);
      o2[k + 4] = (short)f2bf(a1[k] + b1[k]);
    }
    *(short8*)&sg.d2[i] = o2;
  }
}

// ---------------------------------------------------------------------------
// custom attention small kernels (fp32)
// ---------------------------------------------------------------------------
// partial sums of (x1+qpos) over 32-n chunks: xp[b*32+c][512]
__global__ __launch_bounds__(256) void xsum1(const float* x1, const float* qpos, float* xp) {
  const int u = blockIdx.x, b = u >> 5, c = u & 31, tid = threadIdx.x;
  float a0 = 0.f, a1 = 0.f;
  for (int n = c * 32; n < c * 32 + 32; ++n) {
    const long i0 = ((long)(n * 2 + b)) * 512;
    a0 += x1[i0 + tid] + qpos[i0 + tid];
    a1 += x1[i0 + 256 + tid] + qpos[i0 + 256 + tid];
  }
  xp[(long)u * 512 + tid] = a0;
  xp[(long)u * 512 + 256 + tid] = a1;
}

// inline xsum reduce + qs GEMV + s1[z][m] = 0.125*sum_d qs[d]*kT[b][d*8+h][m]
__global__ __launch_bounds__(256) void s1_k(const float* xp, const float* W0, const float* b0,
                                            const float* kT, float* s1) {
  const int z = blockIdx.x, mc = blockIdx.y, b = z >> 3, h = z & 7;
  const int tid = threadIdx.x;
  __shared__ float xsl[512];
  __shared__ float part[4][64];
  __shared__ float qsl[64];
#pragma unroll
  for (int dh = 0; dh < 2; ++dh) {
    const int d = dh * 256 + tid;
    float s = 0.f;
#pragma unroll
    for (int c = 0; c < 32; ++c) s += xp[((long)b * 32 + c) * 512 + d];
    xsl[d] = s;
  }
  __syncthreads();
  const int dd = tid & 63, qd = tid >> 6;
  const int ch = dd * 8 + h;
  float pp = 0.f;
  const float* wrp = W0 + (long)ch * 512 + qd * 128;
#pragma unroll 8
  for (int i = 0; i < 128; ++i) pp += wrp[i] * xsl[qd * 128 + i];
  part[qd][dd] = pp;
  __syncthreads();
  if (tid < 64)
    qsl[tid] = part[0][tid] + part[1][tid] + part[2][tid] + part[3][tid]
               + 1024.0f * b0[tid * 8 + h];
  __syncthreads();
  const int m = mc * 256 + tid;
  float a = 0.f;
#pragma unroll 8
  for (int d2 = 0; d2 < 64; ++d2)
    a += qsl[d2] * kT[((long)b * 512 + d2 * 8 + h) * 2048 + m];
  s1[(long)z * 2048 + m] = 0.125f * a;
}

// per (z, nchunk of 8): softmax rows, accumulate mw[n]-weighted probs -> partials
__global__ __launch_bounds__(256) void pw_k(const float* kT, const float* s1,
                                            const float* mw, float* pwpart) {
  const int z = blockIdx.x & 15, c = blockIdx.x >> 4;
  const int b = z >> 3, h = z & 7;
  const int tid = threadIdx.x, lane = tid & 63, wid = tid >> 6;
  __shared__ float redm[4], reds[4];
  float s1v[8], pwa[8];
#pragma unroll
  for (int i = 0; i < 8; ++i) { s1v[i] = s1[(long)z * 2048 + tid + i * 256]; pwa[i] = 0.f; }
  for (int n = c * 8; n < c * 8 + 8; ++n) {
    const float* kr = kT + ((long)b * 512 + n * 8 + h) * 2048;
    float sv[8];
    float mx = -3e38f;
#pragma unroll
    for (int i = 0; i < 8; ++i) { sv[i] = kr[tid + i * 256] * s1v[i]; mx = fmaxf(mx, sv[i]); }
    mx = wred_max(mx);
    if (lane == 0) redm[wid] = mx;
    __syncthreads();
    mx = fmaxf(fmaxf(redm[0], redm[1]), fmaxf(redm[2], redm[3]));
    float sm = 0.f;
#pragma unroll
    for (int i = 0; i < 8; ++i) { sv[i] = __expf(sv[i] - mx); sm += sv[i]; }
    sm = wred_sum(sm);
    if (lane == 0) reds[wid] = sm;
    __syncthreads();
    sm = reds[0] + reds[1] + reds[2] + reds[3];
    const float wnl = mw[n] / sm;
#pragma unroll
    for (int i = 0; i < 8; ++i) pwa[i] += wnl * sv[i];
    __syncthreads();
  }
#pragma unroll
  for (int i = 0; i < 8; ++i)
    pwpart[((long)c * 16 + z) * 2048 + tid + i * 256] = pwa[i];
}

// t2c[b][d*8+h] = sum_m vT[b][d*8+h][m] * (sum_c pwpart[c][z][m]) + mb
__global__ __launch_bounds__(256) void x2_k(const float* vT, const float* pwpart,
                                            const float* mb, float* t2c) {
  const int z = blockIdx.x, b = z >> 3, h = z & 7;
  const int tid = threadIdx.x, lane = tid & 63, wid = tid >> 6;
  float pwv[32];
#pragma unroll 4
  for (int i = 0; i < 32; ++i) {
    const int m = lane + i * 64;
    float s = 0.f;
#pragma unroll
    for (int c = 0; c < 8; ++c) s += pwpart[((long)c * 16 + z) * 2048 + m];
    pwv[i] = s;
  }
#pragma unroll
  for (int ci = 0; ci < 4; ++ci) {
    const int d = wid * 16 + blockIdx.y * 4 + ci, ch = d * 8 + h;
    const float* vr = vT + ((long)b * 512 + ch) * 2048;
    float acc = 0.f;
#pragma unroll 8
    for (int i = 0; i < 32; ++i) acc += vr[lane + i * 64] * pwv[i];
    acc = wred_sum(acc);
    if (lane == 0) t2c[b * 512 + ch] = acc + mb[0];
  }
}

// ---------------------------------------------------------------------------
extern "C" void kernel_launch(void* const* d_in, const int* in_sizes, int n_in,
                              void* d_out, int out_size, void* d_ws, size_t ws_size,
                              hipStream_t stream) {
  (void)in_sizes; (void)n_in; (void)out_size; (void)ws_size;
  const float* tgt   = (const float*)d_in[0];
  const float* memry = (const float*)d_in[1];
  const float* qpos  = (const float*)d_in[2];
  const float* pos   = (const float*)d_in[3];
  const float* ipw   = (const float*)d_in[4];
  const float* ipb   = (const float*)d_in[5];
  const float* outw  = (const float*)d_in[6];
  const float* outb  = (const float*)d_in[7];
  const float* convw = (const float*)d_in[8];
  const float* convb = (const float*)d_in[9];
  const float* mlpw  = (const float*)d_in[10];
  const float* mlpb  = (const float*)d_in[11];
  const float* l1w   = (const float*)d_in[12];
  const float* l1b   = (const float*)d_in[13];
  const float* l2w   = (const float*)d_in[14];
  const float* l2b   = (const float*)d_in[15];
  const float* lng   = (const float*)d_in[16];
  const float* lnbp  = (const float*)d_in[17];
  const float* fg    = (const float*)d_in[18];
  const float* fbv   = (const float*)d_in[19];

  char* base = (char*)d_ws;
  const long MBy = 1 << 20;
  u16*   qkb   = (u16*)(base + 0);            // 4MB
  u16*   Vtb   = (u16*)(base + 4 * MBy);      // 2MB
  u16*   aob   = (u16*)(base + 6 * MBy);      // 2MB
  u16*   xb    = (u16*)(base + 8 * MBy);      // 2MB
  u16*   xqb   = (u16*)(base + 10 * MBy);     // 2MB
  u16*   mempb = (u16*)(base + 12 * MBy);     // 4MB (memory+pos bf16)
  u16*   memb  = (u16*)(base + 16 * MBy);     // 4MB (memory bf16) -- adjacent!
  u16*   x2nb  = (u16*)(base + 20 * MBy);     // 2MB
  u16*   hb    = (u16*)(base + 22 * MBy);     // 8MB
  float* t2    = (float*)(base + 30 * MBy);   // 4MB
  float* x1    = (float*)(base + 34 * MBy);   // 4MB
  float* x2n   = (float*)(base + 38 * MBy);   // 4MB
  float* fbuf  = (float*)(base + 42 * MBy);   // 4MB
  float* xbuf  = (float*)(base + 46 * MBy);   // 4MB
  u16*   ipwb  = (u16*)(base + 50 * MBy);     // 6MB
  u16*   outwb = (u16*)(base + 56 * MBy);     // 2MB
  u16*   convwb= (u16*)(base + 58 * MBy);     // 6MB
  u16*   l1wb  = (u16*)(base + 64 * MBy);     // 8MB
  u16*   l2wb  = (u16*)(base + 72 * MBy);     // 8MB
  float* xpart = (float*)(base + 80 * MBy);               // 128KB
  float* s1b   = (float*)(base + 80 * MBy + 256 * 1024);  // 128KB
  float* pwpart= (float*)(base + 81 * MBy);               // 1MB
  float* t2c   = (float*)(base + 83 * MBy);               // 4KB
  float* kvall = (float*)(base + 96 * MBy);               // 64MB [16][512][2048]

  // one-time conversions (single launch) + ALL-layer conv k/v projections
  {
    CvtAll c;
    c.seg[0] = { ipw,   nullptr, ipwb,  nullptr, 1536, 0 };
    c.seg[1] = { outw,  nullptr, outwb, nullptr,  512, 0 };
    c.seg[2] = { convw, nullptr, convwb,nullptr, 1536, 0 };
    c.seg[3] = { l1w,   nullptr, l1wb,  nullptr, 2048, 0 };
    c.seg[4] = { l2w,   nullptr, l2wb,  nullptr, 2048, 0 };
    c.seg[5] = { memry, pos,     memb,  mempb,   1024, 1 };
    c.seg[6] = { tgt,   qpos,    xb,    xqb,      512, 1 };
    cvt_all<<<dim3(9216), dim3(256), 0, stream>>>(c);
  }
  convkv_k<<<dim3(1024), dim3(256), 0, stream>>>(mempb, convwb, convb, kvall);

  for (int l = 0; l < 4; ++l) {
    const float* xin = l ? xbuf : tgt;
    const float* kT = kvall + (long)l * 4194304;
    const float* vT = kT + 2097152;

    // A: grouped qk-proj + v-proj (64x64 tiles, 768 blocks)
    {
      GemmP q{};
      q.A = xqb; q.lda = 512; q.B = ipwb + (long)l * 786432; q.ldb = 512;
      q.C = qkb; q.crs = 1024; q.ccs = 1; q.cbf16 = 1;
      q.bias = ipb + (long)l * 1536;
      q.K = 512; q.azi = q.bzi = q.czi = 1; q.scale = 1.0f;
      GemmP v{};
      v.A = xb; v.lda = 512; v.B = ipwb + (long)l * 786432 + 524288; v.ldb = 512;
      v.C = Vtb; v.cm = 1; v.bias = ipb + (long)l * 1536 + 1024;
      v.K = 512; v.azi = v.bzi = v.czi = 1; v.scale = 1.0f;
      qkv2_k<<<dim3(768), dim3(256), 0, stream>>>(q, v);
    }
    // B: flash attention
    flash_attn<<<dim3(16, 16), dim3(256), 0, stream>>>(qkb, Vtb, aob);
    // C: out projection
    {
      GemmP o{};
      o.A = aob; o.lda = 512; o.B = outwb + (long)l * 262144; o.ldb = 512;
      o.C = t2; o.crs = 512; o.ccs = 1; o.bias = outb + l * 512;
      o.K = 512; o.azi = o.bzi = o.czi = 1; o.scale = 1.0f;
      gemm_k<32, 64><<<dim3(8, 64, 1), dim3(256), 0, stream>>>(o);
    }
    // D: LN1
    ln512<<<dim3(512), dim3(256), 0, stream>>>(t2, xin, 1, lng + (l * 3) * 512,
                                               lnbp + (l * 3) * 512, x1, nullptr,
                                               nullptr, nullptr);
    // E-H: custom attention
    xsum1<<<dim3(64), dim3(256), 0, stream>>>(x1, qpos, xpart);
    s1_k<<<dim3(16, 8), dim3(256), 0, stream>>>(xpart, convw + ((long)l * 3) * 262144,
                                                convb + (l * 3) * 512, kT, s1b);
    pw_k<<<dim3(128), dim3(256), 0, stream>>>(kT, s1b, mlpw + l * 64, pwpart);
    x2_k<<<dim3(16, 4), dim3(256), 0, stream>>>(vT, pwpart, mlpb + l, t2c);
    // I: LN2
    ln512<<<dim3(512), dim3(256), 0, stream>>>(x1, t2c, 2, lng + (l * 3 + 1) * 512,
                                               lnbp + (l * 3 + 1) * 512, x2n, x2nb,
                                               nullptr, nullptr);
    // J: FFN1 (64x64 tiles)
    {
      GemmP f1{};
      f1.A = x2nb; f1.lda = 512; f1.B = l1wb + (long)l * 1048576; f1.ldb = 512;
      f1.C = hb; f1.crs = 2048; f1.ccs = 1; f1.cbf16 = 1; f1.relu = 1;
      f1.bias = l1b + l * 2048;
      f1.K = 512; f1.azi = f1.bzi = f1.czi = 1; f1.scale = 1.0f;
      gemm_k<64, 64><<<dim3(32, 32, 1), dim3(256), 0, stream>>>(f1);
    }
    // K: FFN2
    {
      GemmP f2{};
      f2.A = hb; f2.lda = 2048; f2.B = l2wb + (long)l * 1048576; f2.ldb = 2048;
      f2.C = fbuf; f2.crs = 512; f2.ccs = 1; f2.bias = l2b + l * 512;
      f2.K = 2048; f2.azi = f2.bzi = f2.czi = 1; f2.scale = 1.0f;
      gemm_k<32, 64><<<dim3(8, 64, 1), dim3(256), 0, stream>>>(f2);
    }
    // L: LN3 (+ next layer's xb/xqb bf16) — fused with final LN on last layer
    if (l < 3) {
      ln512<<<dim3(512), dim3(256), 0, stream>>>(fbuf, x2n, 1, lng + (l * 3 + 2) * 512,
                                                 lnbp + (l * 3 + 2) * 512, xbuf, xb,
                                                 qpos, xqb);
    } else {
      ln512_last<<<dim3(512), dim3(256), 0, stream>>>(fbuf, x2n,
                                                      lng + (l * 3 + 2) * 512,
                                                      lnbp + (l * 3 + 2) * 512,
                                                      fg, fbv, (float*)d_out);
    }
  }
}